// Round 4
// baseline (151.579 us; speedup 1.0000x reference)
//
#include <hip/hip_runtime.h>

#define N_NODES 20000
#define N_EDGES 640000
#define HIDDEN  128
#define CAP     96        // max in-degree; Binomial(640K,1/20K) tail @96 ~ e^-45
#define DEG_PAD 16        // one counter per 64B line
#define LDSP    136       // LDS agg row pitch in shorts (272B: 16B-aligned, bank-friendly)

typedef unsigned short bf16_t;
typedef __attribute__((ext_vector_type(8))) short short8;            // 8 bf16
typedef __attribute__((ext_vector_type(8))) unsigned short ushort8_t; // 8 u16
typedef __attribute__((ext_vector_type(4))) float floatx4;            // MFMA C/D

__device__ __forceinline__ bf16_t f2bf(float f) {
    union { float f; unsigned int i; } v; v.f = f;
    unsigned int x = v.i + 0x7FFFu + ((v.i >> 16) & 1u);   // RNE
    return (bf16_t)(x >> 16);
}
__device__ __forceinline__ float bflo(unsigned u) {
    union { unsigned i; float f; } v; v.i = u << 16; return v.f;
}
__device__ __forceinline__ float bfhi(unsigned u) {
    union { unsigned i; float f; } v; v.i = u & 0xFFFF0000u; return v.f;
}

// --- k1: feat fp32->bf16  +  bucket fill  +  Bp weight pack ---------------
// Single unsharded bucket (R3 sharding regressed). Padded counters.
// Bp t = ((kt*8 + nt)*64 + lane)*8 + j  holds  B[k][n]:
//   k = kt*32 + (lane>>4)*8 + j   (K = 256: k<128 -> W_l (agg), k>=128 -> W_r (feat))
//   n = nt*16 + (lane&15)         (N = 128, output dim)
__global__ __launch_bounds__(256) void prep_fill_kernel(
        const float* __restrict__ feat,
        const float* __restrict__ Wl,
        const float* __restrict__ Wr,
        const int* __restrict__ eidx,
        bf16_t* __restrict__ feat_bf,
        bf16_t* __restrict__ Bp,
        int* __restrict__ deg,                 // pre-zeroed, stride DEG_PAD
        unsigned short* __restrict__ bucket) {
    int t = blockIdx.x * 256 + threadIdx.x;    // 0 .. 639999 exactly
    // feat convert: 640000 float4s
    float4 v = ((const float4*)feat)[t];
    ushort4 o = { f2bf(v.x), f2bf(v.y), f2bf(v.z), f2bf(v.w) };
    ((ushort4*)feat_bf)[t] = o;
    // edge fill: one atomic slot-claim per edge
    int src = eidx[t];
    int dst = eidx[N_EDGES + t];
    int pos = atomicAdd(&deg[dst * DEG_PAD], 1);
    if (pos < CAP) bucket[dst * CAP + pos] = (unsigned short)src;
    // Bp pack: 32768 entries (K=256 x N=128)
    if (t < 2 * HIDDEN * HIDDEN) {
        int j    = t & 7;
        int lane = (t >> 3) & 63;
        int nt   = (t >> 9) & 7;
        int kt   = t >> 12;
        int n = nt * 16 + (lane & 15);
        int k = kt * 32 + (lane >> 4) * 8 + j;
        float w = (k < HIDDEN) ? Wl[n * HIDDEN + k] : Wr[n * HIDDEN + (k - HIDDEN)];
        Bp[t] = f2bf(w);
    }
}

// --- k2 (fused): per-block gather+mean of its 16 rows -> LDS -> MFMA GEMM --
// Gather: wave w aggregates nodes row0+w*4 .. +3 (16 rows in flight each),
// lane holds cols {2*lane, 2*lane+1}; writes packed u32 to LDS (pitch 136
// shorts: write banks = lane&31, 2-way = free; ds_read_b128 A-frag = 2-way).
// GEMM: out = [agg | feat] @ [W_l ; W_r]^T + b, A-frag kt<4 from LDS,
// kt>=4 from feat_bf. C/D: col=lane&15, row=(lane>>4)*4+r  [m89-verified]
__global__ __launch_bounds__(256) void agg_gemm_kernel(
        const bf16_t* __restrict__ feat_bf,
        const bf16_t* __restrict__ Bp,
        const float* __restrict__ bl,
        const int* __restrict__ deg,
        const unsigned short* __restrict__ bucket,
        float* __restrict__ out) {
    __shared__ bf16_t aggT[16 * LDSP];
    int wave = threadIdx.x >> 6;
    int lane = threadIdx.x & 63;
    int row0 = blockIdx.x * 16;
    const unsigned* y = (const unsigned*)feat_bf;     // packed bf16 pairs

    for (int nn = 0; nn < 4; ++nn) {
        int node = row0 + wave * 4 + nn;
        int d_true = deg[node * DEG_PAD];
        int d = min(d_true, CAP);
        const unsigned short* row = bucket + (size_t)node * CAP;
        float ax0=0,ay0=0, ax1=0,ay1=0, ax2=0,ay2=0, ax3=0,ay3=0;
        int i = 0;
        for (; i + 16 <= d; i += 16) {
            ushort8_t s0 = *(const ushort8_t*)(row + i);
            ushort8_t s1 = *(const ushort8_t*)(row + i + 8);
            unsigned u0 = y[(int)s0[0] * 64 + lane];
            unsigned u1 = y[(int)s0[1] * 64 + lane];
            unsigned u2 = y[(int)s0[2] * 64 + lane];
            unsigned u3 = y[(int)s0[3] * 64 + lane];
            unsigned u4 = y[(int)s0[4] * 64 + lane];
            unsigned u5 = y[(int)s0[5] * 64 + lane];
            unsigned u6 = y[(int)s0[6] * 64 + lane];
            unsigned u7 = y[(int)s0[7] * 64 + lane];
            unsigned w0 = y[(int)s1[0] * 64 + lane];
            unsigned w1 = y[(int)s1[1] * 64 + lane];
            unsigned w2 = y[(int)s1[2] * 64 + lane];
            unsigned w3 = y[(int)s1[3] * 64 + lane];
            unsigned w4 = y[(int)s1[4] * 64 + lane];
            unsigned w5 = y[(int)s1[5] * 64 + lane];
            unsigned w6 = y[(int)s1[6] * 64 + lane];
            unsigned w7 = y[(int)s1[7] * 64 + lane];
            ax0 += bflo(u0); ay0 += bfhi(u0);
            ax1 += bflo(u1); ay1 += bfhi(u1);
            ax2 += bflo(u2); ay2 += bfhi(u2);
            ax3 += bflo(u3); ay3 += bfhi(u3);
            ax0 += bflo(u4); ay0 += bfhi(u4);
            ax1 += bflo(u5); ay1 += bfhi(u5);
            ax2 += bflo(u6); ay2 += bfhi(u6);
            ax3 += bflo(u7); ay3 += bfhi(u7);
            ax0 += bflo(w0); ay0 += bfhi(w0);
            ax1 += bflo(w1); ay1 += bfhi(w1);
            ax2 += bflo(w2); ay2 += bfhi(w2);
            ax3 += bflo(w3); ay3 += bfhi(w3);
            ax0 += bflo(w4); ay0 += bfhi(w4);
            ax1 += bflo(w5); ay1 += bfhi(w5);
            ax2 += bflo(w6); ay2 += bfhi(w6);
            ax3 += bflo(w7); ay3 += bfhi(w7);
        }
        for (; i + 8 <= d; i += 8) {
            ushort8_t s = *(const ushort8_t*)(row + i);
            unsigned u0 = y[(int)s[0] * 64 + lane];
            unsigned u1 = y[(int)s[1] * 64 + lane];
            unsigned u2 = y[(int)s[2] * 64 + lane];
            unsigned u3 = y[(int)s[3] * 64 + lane];
            unsigned u4 = y[(int)s[4] * 64 + lane];
            unsigned u5 = y[(int)s[5] * 64 + lane];
            unsigned u6 = y[(int)s[6] * 64 + lane];
            unsigned u7 = y[(int)s[7] * 64 + lane];
            ax0 += bflo(u0); ay0 += bfhi(u0);
            ax1 += bflo(u1); ay1 += bfhi(u1);
            ax2 += bflo(u2); ay2 += bfhi(u2);
            ax3 += bflo(u3); ay3 += bfhi(u3);
            ax0 += bflo(u4); ay0 += bfhi(u4);
            ax1 += bflo(u5); ay1 += bfhi(u5);
            ax2 += bflo(u6); ay2 += bfhi(u6);
            ax3 += bflo(u7); ay3 += bfhi(u7);
        }
        for (; i < d; ++i) {
            unsigned u = y[(int)row[i] * 64 + lane];
            ax0 += bflo(u); ay0 += bfhi(u);
        }
        float inv = 1.0f / fmaxf((float)d_true, 1.0f);
        float sx = (ax0 + ax1 + ax2 + ax3) * inv;
        float sy = (ay0 + ay1 + ay2 + ay3) * inv;
        unsigned pk = (unsigned)f2bf(sx) | ((unsigned)f2bf(sy) << 16);
        // row (wave*4+nn), cols {2*lane, 2*lane+1}
        ((unsigned*)&aggT[(wave * 4 + nn) * LDSP])[lane] = pk;
    }
    __syncthreads();

    // --- GEMM phase ---
    int m    = lane & 15;
    int quad = lane >> 4;
    floatx4 acc[8];
    floatx4 zf = {0.f, 0.f, 0.f, 0.f};
#pragma unroll
    for (int nt = 0; nt < 8; ++nt) acc[nt] = zf;

    const short8* bp = (const short8*)Bp;
#pragma unroll
    for (int kt = 0; kt < 8; ++kt) {
        short8 afrag;
        if (kt < 4) {
            afrag = *(const short8*)(&aggT[m * LDSP + kt * 32 + quad * 8]);
        } else {
            afrag = *(const short8*)(feat_bf + (size_t)(row0 + m) * HIDDEN
                                     + (kt - 4) * 32 + quad * 8);
        }
#pragma unroll
        for (int nt = 0; nt < 8; ++nt) {
            short8 bfrag = bp[(kt * 8 + nt) * 64 + lane];
            acc[nt] = __builtin_amdgcn_mfma_f32_16x16x32_bf16(afrag, bfrag, acc[nt], 0, 0, 0);
        }
    }
    int col = lane & 15;
#pragma unroll
    for (int nt = 0; nt < 8; ++nt) {
        float b = bl[nt * 16 + col];
#pragma unroll
        for (int r = 0; r < 4; ++r) {
            int row = row0 + quad * 4 + r;
            out[(size_t)row * HIDDEN + nt * 16 + col] = acc[nt][r] + b;
        }
    }
}

extern "C" void kernel_launch(void* const* d_in, const int* in_sizes, int n_in,
                              void* d_out, int out_size, void* d_ws, size_t ws_size,
                              hipStream_t stream) {
    const float* feat = (const float*)d_in[0];
    const int*   eidx = (const int*)d_in[1];
    const float* Wl   = (const float*)d_in[2];
    const float* bl   = (const float*)d_in[3];
    const float* Wr   = (const float*)d_in[4];
    float* out = (float*)d_out;

    // workspace layout (~15 MB; ws is 256 MiB); all sections 16B-aligned
    int*            deg     = (int*)d_ws;                                   // 20000*16 int
    unsigned short* bucket  = (unsigned short*)(deg + N_NODES * DEG_PAD);   // 20000*96 u16
    bf16_t*         Bp      = (bf16_t*)(bucket + (size_t)N_NODES * CAP);    // 32768 bf16
    bf16_t*         feat_bf = Bp + 2 * HIDDEN * HIDDEN;                     // 20000*128 bf16

    hipMemsetAsync(deg, 0, (size_t)N_NODES * DEG_PAD * sizeof(int), stream);

    prep_fill_kernel<<<N_EDGES / 256, 256, 0, stream>>>(
        feat, Wl, Wr, eidx, feat_bf, Bp, deg, bucket);
    agg_gemm_kernel<<<N_NODES / 16, 256, 0, stream>>>(
        feat_bf, Bp, bl, deg, bucket, out);
}

// Round 5
// 142.564 us; speedup vs baseline: 1.0632x; 1.0632x over previous
//
#include <hip/hip_runtime.h>

#define N_NODES 20000
#define N_EDGES 640000
#define HIDDEN  128
#define CAP     96        // max in-degree; Binomial(640K,1/20K) tail @96 ~ e^-45
#define DEG_PAD 16        // one counter per 64B line

typedef unsigned short bf16_t;
typedef __attribute__((ext_vector_type(8))) short short8;            // 8 bf16
typedef __attribute__((ext_vector_type(8))) unsigned short ushort8_t; // 8 u16
typedef __attribute__((ext_vector_type(4))) float floatx4;            // MFMA C/D

__device__ __forceinline__ bf16_t f2bf(float f) {
    union { float f; unsigned int i; } v; v.f = f;
    unsigned int x = v.i + 0x7FFFu + ((v.i >> 16) & 1u);   // RNE
    return (bf16_t)(x >> 16);
}
__device__ __forceinline__ float bflo(unsigned u) {
    union { unsigned i; float f; } v; v.i = u << 16; return v.f;
}
__device__ __forceinline__ float bfhi(unsigned u) {
    union { unsigned i; float f; } v; v.i = u & 0xFFFF0000u; return v.f;
}

// --- k1: feat fp32->bf16  +  bucket fill  +  Bp weight pack ---------------
// (R2-verified form.) Bp t = ((kt*8 + nt)*64 + lane)*8 + j holds B[k][n]:
//   k = kt*32 + (lane>>4)*8 + j   (K = 256: k<128 -> W_l (agg), k>=128 -> W_r (feat))
//   n = nt*16 + (lane&15)         (N = 128, output dim)
__global__ __launch_bounds__(256) void prep_fill_kernel(
        const float* __restrict__ feat,
        const float* __restrict__ Wl,
        const float* __restrict__ Wr,
        const int* __restrict__ eidx,
        bf16_t* __restrict__ feat_bf,
        bf16_t* __restrict__ Bp,
        int* __restrict__ deg,                 // pre-zeroed, stride DEG_PAD
        unsigned short* __restrict__ bucket) {
    int t = blockIdx.x * 256 + threadIdx.x;    // 0 .. 639999 exactly
    // feat convert: 640000 float4s
    float4 v = ((const float4*)feat)[t];
    ushort4 o = { f2bf(v.x), f2bf(v.y), f2bf(v.z), f2bf(v.w) };
    ((ushort4*)feat_bf)[t] = o;
    // edge fill: one atomic slot-claim per edge
    int src = eidx[t];
    int dst = eidx[N_EDGES + t];
    int pos = atomicAdd(&deg[dst * DEG_PAD], 1);
    if (pos < CAP) bucket[dst * CAP + pos] = (unsigned short)src;
    // Bp pack: 32768 entries (K=256 x N=128)
    if (t < 2 * HIDDEN * HIDDEN) {
        int j    = t & 7;
        int lane = (t >> 3) & 63;
        int nt   = (t >> 9) & 7;
        int kt   = t >> 12;
        int n = nt * 16 + (lane & 15);
        int k = kt * 32 + (lane >> 4) * 8 + j;
        float w = (k < HIDDEN) ? Wl[n * HIDDEN + k] : Wr[n * HIDDEN + (k - HIDDEN)];
        Bp[t] = f2bf(w);
    }
}

// --- k2: split-pass agg — pass `half` gathers cols [half*64, half*64+64) ---
// Per-pass working set = 20000 rows x 128B = 2.56 MB -> fits each XCD's 4 MiB
// L2 (full table, 5.1 MB, does not). One wave per node: lanes 0-31 gather the
// half-row of even slots, lanes 32-63 of odd slots (2x128B per load instr);
// cross-sub reduce via shfl_xor(32). Full 20000-wave parallelism.
__global__ __launch_bounds__(256) void agg_half_kernel(
        const bf16_t* __restrict__ feat_bf,
        const int* __restrict__ deg,
        const unsigned short* __restrict__ bucket,
        bf16_t* __restrict__ agg,
        int half) {
    int wid  = (blockIdx.x * 256 + threadIdx.x) >> 6;
    int lane = threadIdx.x & 63;
    if (wid >= N_NODES) return;
    int c   = lane & 31;          // u32 column within the 128B half-row
    int sub = lane >> 5;          // 0: even slots, 1: odd slots
    int d_true = deg[wid * DEG_PAD];
    int d = min(d_true, CAP);
    const unsigned short* row = bucket + (size_t)wid * CAP;   // 192B-aligned
    const unsigned* yh = (const unsigned*)feat_bf + half * 32 + c;

    float ax0=0,ay0=0, ax1=0,ay1=0, ax2=0,ay2=0, ax3=0,ay3=0;
    int k = 0;
    for (; k + 32 <= d; k += 32) {            // 16 loads in flight
        ushort8_t s0 = *(const ushort8_t*)(row + k);
        ushort8_t s1 = *(const ushort8_t*)(row + k + 8);
        ushort8_t s2 = *(const ushort8_t*)(row + k + 16);
        ushort8_t s3 = *(const ushort8_t*)(row + k + 24);
        int a0 = sub ? (int)s0[1] : (int)s0[0];
        int a1 = sub ? (int)s0[3] : (int)s0[2];
        int a2 = sub ? (int)s0[5] : (int)s0[4];
        int a3 = sub ? (int)s0[7] : (int)s0[6];
        int a4 = sub ? (int)s1[1] : (int)s1[0];
        int a5 = sub ? (int)s1[3] : (int)s1[2];
        int a6 = sub ? (int)s1[5] : (int)s1[4];
        int a7 = sub ? (int)s1[7] : (int)s1[6];
        int b0 = sub ? (int)s2[1] : (int)s2[0];
        int b1 = sub ? (int)s2[3] : (int)s2[2];
        int b2 = sub ? (int)s2[5] : (int)s2[4];
        int b3 = sub ? (int)s2[7] : (int)s2[6];
        int b4 = sub ? (int)s3[1] : (int)s3[0];
        int b5 = sub ? (int)s3[3] : (int)s3[2];
        int b6 = sub ? (int)s3[5] : (int)s3[4];
        int b7 = sub ? (int)s3[7] : (int)s3[6];
        unsigned u0 = yh[a0 * 64];
        unsigned u1 = yh[a1 * 64];
        unsigned u2 = yh[a2 * 64];
        unsigned u3 = yh[a3 * 64];
        unsigned u4 = yh[a4 * 64];
        unsigned u5 = yh[a5 * 64];
        unsigned u6 = yh[a6 * 64];
        unsigned u7 = yh[a7 * 64];
        unsigned v0 = yh[b0 * 64];
        unsigned v1 = yh[b1 * 64];
        unsigned v2 = yh[b2 * 64];
        unsigned v3 = yh[b3 * 64];
        unsigned v4 = yh[b4 * 64];
        unsigned v5 = yh[b5 * 64];
        unsigned v6 = yh[b6 * 64];
        unsigned v7 = yh[b7 * 64];
        ax0 += bflo(u0); ay0 += bfhi(u0);
        ax1 += bflo(u1); ay1 += bfhi(u1);
        ax2 += bflo(u2); ay2 += bfhi(u2);
        ax3 += bflo(u3); ay3 += bfhi(u3);
        ax0 += bflo(u4); ay0 += bfhi(u4);
        ax1 += bflo(u5); ay1 += bfhi(u5);
        ax2 += bflo(u6); ay2 += bfhi(u6);
        ax3 += bflo(u7); ay3 += bfhi(u7);
        ax0 += bflo(v0); ay0 += bfhi(v0);
        ax1 += bflo(v1); ay1 += bfhi(v1);
        ax2 += bflo(v2); ay2 += bfhi(v2);
        ax3 += bflo(v3); ay3 += bfhi(v3);
        ax0 += bflo(v4); ay0 += bfhi(v4);
        ax1 += bflo(v5); ay1 += bfhi(v5);
        ax2 += bflo(v6); ay2 += bfhi(v6);
        ax3 += bflo(v7); ay3 += bfhi(v7);
    }
    for (; k + 16 <= d; k += 16) {            // 8 loads in flight
        ushort8_t s0 = *(const ushort8_t*)(row + k);
        ushort8_t s1 = *(const ushort8_t*)(row + k + 8);
        int a0 = sub ? (int)s0[1] : (int)s0[0];
        int a1 = sub ? (int)s0[3] : (int)s0[2];
        int a2 = sub ? (int)s0[5] : (int)s0[4];
        int a3 = sub ? (int)s0[7] : (int)s0[6];
        int a4 = sub ? (int)s1[1] : (int)s1[0];
        int a5 = sub ? (int)s1[3] : (int)s1[2];
        int a6 = sub ? (int)s1[5] : (int)s1[4];
        int a7 = sub ? (int)s1[7] : (int)s1[6];
        unsigned u0 = yh[a0 * 64];
        unsigned u1 = yh[a1 * 64];
        unsigned u2 = yh[a2 * 64];
        unsigned u3 = yh[a3 * 64];
        unsigned u4 = yh[a4 * 64];
        unsigned u5 = yh[a5 * 64];
        unsigned u6 = yh[a6 * 64];
        unsigned u7 = yh[a7 * 64];
        ax0 += bflo(u0); ay0 += bfhi(u0);
        ax1 += bflo(u1); ay1 += bfhi(u1);
        ax2 += bflo(u2); ay2 += bfhi(u2);
        ax3 += bflo(u3); ay3 += bfhi(u3);
        ax0 += bflo(u4); ay0 += bfhi(u4);
        ax1 += bflo(u5); ay1 += bfhi(u5);
        ax2 += bflo(u6); ay2 += bfhi(u6);
        ax3 += bflo(u7); ay3 += bfhi(u7);
    }
    for (; k + 2 <= d; k += 2) {              // slot pair
        int ia = (int)row[k + sub];
        unsigned u = yh[ia * 64];
        ax0 += bflo(u); ay0 += bfhi(u);
    }
    if (k < d) {                              // odd remainder: sub 0 only
        int ia = (int)row[k];
        unsigned u = yh[ia * 64];
        u = sub ? 0u : u;
        ax0 += bflo(u); ay0 += bfhi(u);
    }
    float sx = (ax0 + ax1) + (ax2 + ax3);
    float sy = (ay0 + ay1) + (ay2 + ay3);
    sx += __shfl_xor(sx, 32);
    sy += __shfl_xor(sy, 32);
    if (sub == 0) {
        float inv = 1.0f / fmaxf((float)d_true, 1.0f);
        unsigned pk = (unsigned)f2bf(sx * inv) | ((unsigned)f2bf(sy * inv) << 16);
        ((unsigned*)agg)[wid * 64 + half * 32 + c] = pk;
    }
}

// --- k3: MFMA GEMM  out = [agg | feat] @ [W_l ; W_r]^T + b  (fp32 out) -----
// (R2-verified form.) A-frag: lane holds A[m=lane&15][k=kt*32+(lane>>4)*8+j];
// kt<4 from agg, kt>=4 from feat_bf. C/D: col=lane&15, row=(lane>>4)*4+r
__global__ __launch_bounds__(256) void gemm_out_kernel(
        const bf16_t* __restrict__ agg,
        const bf16_t* __restrict__ feat_bf,
        const bf16_t* __restrict__ Bp,
        const float* __restrict__ bl,
        float* __restrict__ out) {
    int wid = blockIdx.x * 4 + (threadIdx.x >> 6);   // 16-row M-tile
    if (wid >= N_NODES / 16) return;
    int lane = threadIdx.x & 63;
    int m    = lane & 15;
    int quad = lane >> 4;
    int row0 = wid * 16;

    floatx4 acc[8];
    floatx4 zf = {0.f, 0.f, 0.f, 0.f};
#pragma unroll
    for (int nt = 0; nt < 8; ++nt) acc[nt] = zf;

    const short8* bp = (const short8*)Bp;
#pragma unroll
    for (int kt = 0; kt < 8; ++kt) {
        const bf16_t* abase = (kt < 4)
            ? (agg     + (size_t)(row0 + m) * HIDDEN + kt * 32 + quad * 8)
            : (feat_bf + (size_t)(row0 + m) * HIDDEN + (kt - 4) * 32 + quad * 8);
        short8 afrag = *(const short8*)abase;
#pragma unroll
        for (int nt = 0; nt < 8; ++nt) {
            short8 bfrag = bp[(kt * 8 + nt) * 64 + lane];
            acc[nt] = __builtin_amdgcn_mfma_f32_16x16x32_bf16(afrag, bfrag, acc[nt], 0, 0, 0);
        }
    }
    int col = lane & 15;
#pragma unroll
    for (int nt = 0; nt < 8; ++nt) {
        float b = bl[nt * 16 + col];
#pragma unroll
        for (int r = 0; r < 4; ++r) {
            int row = row0 + quad * 4 + r;
            out[(size_t)row * HIDDEN + nt * 16 + col] = acc[nt][r] + b;
        }
    }
}

extern "C" void kernel_launch(void* const* d_in, const int* in_sizes, int n_in,
                              void* d_out, int out_size, void* d_ws, size_t ws_size,
                              hipStream_t stream) {
    const float* feat = (const float*)d_in[0];
    const int*   eidx = (const int*)d_in[1];
    const float* Wl   = (const float*)d_in[2];
    const float* bl   = (const float*)d_in[3];
    const float* Wr   = (const float*)d_in[4];
    float* out = (float*)d_out;

    // workspace layout (~15 MB; ws is 256 MiB); all sections 16B-aligned
    int*            deg     = (int*)d_ws;                                   // 20000*16 int
    unsigned short* bucket  = (unsigned short*)(deg + N_NODES * DEG_PAD);   // 20000*96 u16
    bf16_t*         Bp      = (bf16_t*)(bucket + (size_t)N_NODES * CAP);    // 32768 bf16
    bf16_t*         feat_bf = Bp + 2 * HIDDEN * HIDDEN;                     // 20000*128 bf16
    bf16_t*         agg     = feat_bf + (size_t)N_NODES * HIDDEN;           // 20000*128 bf16

    hipMemsetAsync(deg, 0, (size_t)N_NODES * DEG_PAD * sizeof(int), stream);

    prep_fill_kernel<<<N_EDGES / 256, 256, 0, stream>>>(
        feat, Wl, Wr, eidx, feat_bf, Bp, deg, bucket);
    agg_half_kernel<<<(N_NODES * 64) / 256, 256, 0, stream>>>(
        feat_bf, deg, bucket, agg, 0);
    agg_half_kernel<<<(N_NODES * 64) / 256, 256, 0, stream>>>(
        feat_bf, deg, bucket, agg, 1);
    gemm_out_kernel<<<(N_NODES / 16 + 3) / 4, 256, 0, stream>>>(
        agg, feat_bf, Bp, bl, out);
}

// Round 6
// 130.502 us; speedup vs baseline: 1.1615x; 1.0924x over previous
//
#include <hip/hip_runtime.h>

#define N_NODES 20000
#define N_EDGES 640000
#define HIDDEN  128
#define CAP     96        // max in-degree; Binomial(640K,1/20K) tail @96 ~ e^-45
#define DEG_PAD 16        // one counter per 64B line

typedef unsigned short bf16_t;
typedef __attribute__((ext_vector_type(8))) short short8;            // 8 bf16
typedef __attribute__((ext_vector_type(4))) float floatx4;            // MFMA C/D

__device__ __forceinline__ bf16_t f2bf(float f) {
    union { float f; unsigned int i; } v; v.f = f;
    unsigned int x = v.i + 0x7FFFu + ((v.i >> 16) & 1u);   // RNE
    return (bf16_t)(x >> 16);
}
__device__ __forceinline__ float bflo(unsigned u) {
    union { unsigned i; float f; } v; v.i = u << 16; return v.f;
}
__device__ __forceinline__ float bfhi(unsigned u) {
    union { unsigned i; float f; } v; v.i = u & 0xFFFF0000u; return v.f;
}

// --- k1: feat fp32->bf16  +  bucket fill  +  Bp weight pack ---------------
// (R2-verified form.) Bp t = ((kt*8 + nt)*64 + lane)*8 + j holds B[k][n]:
//   k = kt*32 + (lane>>4)*8 + j   (K = 256: k<128 -> W_l (agg), k>=128 -> W_r (feat))
//   n = nt*16 + (lane&15)         (N = 128, output dim)
__global__ __launch_bounds__(256) void prep_fill_kernel(
        const float* __restrict__ feat,
        const float* __restrict__ Wl,
        const float* __restrict__ Wr,
        const int* __restrict__ eidx,
        bf16_t* __restrict__ feat_bf,
        bf16_t* __restrict__ Bp,
        int* __restrict__ deg,                 // pre-zeroed, stride DEG_PAD
        unsigned short* __restrict__ bucket) {
    int t = blockIdx.x * 256 + threadIdx.x;    // 0 .. 639999 exactly
    // feat convert: 640000 float4s
    float4 v = ((const float4*)feat)[t];
    ushort4 o = { f2bf(v.x), f2bf(v.y), f2bf(v.z), f2bf(v.w) };
    ((ushort4*)feat_bf)[t] = o;
    // edge fill: one atomic slot-claim per edge
    int src = eidx[t];
    int dst = eidx[N_EDGES + t];
    int pos = atomicAdd(&deg[dst * DEG_PAD], 1);
    if (pos < CAP) bucket[dst * CAP + pos] = (unsigned short)src;
    // Bp pack: 32768 entries (K=256 x N=128)
    if (t < 2 * HIDDEN * HIDDEN) {
        int j    = t & 7;
        int lane = (t >> 3) & 63;
        int nt   = (t >> 9) & 7;
        int kt   = t >> 12;
        int n = nt * 16 + (lane & 15);
        int k = kt * 32 + (lane >> 4) * 8 + j;
        float w = (k < HIDDEN) ? Wl[n * HIDDEN + k] : Wr[n * HIDDEN + (k - HIDDEN)];
        Bp[t] = f2bf(w);
    }
}

// --- k2: agg[i] = mean_{j in N(i)} feat_bf[j] — 4 rows per load instr ------
// Lane quads: group g = lane>>4 owns neighbor-row k+g; each lane loads 16B
// (uint4) at feat_bf[idx*128 + (lane&15)*8] -> one instruction = 4 full rows
// (1 KiB). 4x fewer VMEM instructions than the 1-row/instr form (R5 showed
// the gather is request-bound, not byte-bound). Cross-group reduce at end:
// shfl_xor(16) + shfl_xor(32) on the 8 per-lane column sums.
__global__ __launch_bounds__(256) void agg_kernel(
        const bf16_t* __restrict__ feat_bf,
        const int* __restrict__ deg,
        const unsigned short* __restrict__ bucket,
        bf16_t* __restrict__ agg) {
    int wid  = (blockIdx.x * 256 + threadIdx.x) >> 6;
    int lane = threadIdx.x & 63;
    if (wid >= N_NODES) return;
    int grp = lane >> 4;       // which row of the quad
    int c   = lane & 15;       // 16B chunk within row (bf16 cols 8c..8c+7)
    int d_true = deg[wid * DEG_PAD];
    int d = min(d_true, CAP);
    const unsigned short* row = bucket + (size_t)wid * CAP;   // 192B stride
    const uint4* yq = (const uint4*)feat_bf;   // row idx -> 16 uint4 chunks

    float a0=0,a1=0,a2=0,a3=0,a4=0,a5=0,a6=0,a7=0;
    int k = 0;
    for (; k + 16 <= d; k += 16) {            // 16 rows / 4 loads in flight
        int i0 = (int)row[k      + grp];
        int i1 = (int)row[k + 4  + grp];
        int i2 = (int)row[k + 8  + grp];
        int i3 = (int)row[k + 12 + grp];
        uint4 u0 = yq[i0 * 16 + c];
        uint4 u1 = yq[i1 * 16 + c];
        uint4 u2 = yq[i2 * 16 + c];
        uint4 u3 = yq[i3 * 16 + c];
        a0 += bflo(u0.x); a1 += bfhi(u0.x); a2 += bflo(u0.y); a3 += bfhi(u0.y);
        a4 += bflo(u0.z); a5 += bfhi(u0.z); a6 += bflo(u0.w); a7 += bfhi(u0.w);
        a0 += bflo(u1.x); a1 += bfhi(u1.x); a2 += bflo(u1.y); a3 += bfhi(u1.y);
        a4 += bflo(u1.z); a5 += bfhi(u1.z); a6 += bflo(u1.w); a7 += bfhi(u1.w);
        a0 += bflo(u2.x); a1 += bfhi(u2.x); a2 += bflo(u2.y); a3 += bfhi(u2.y);
        a4 += bflo(u2.z); a5 += bfhi(u2.z); a6 += bflo(u2.w); a7 += bfhi(u2.w);
        a0 += bflo(u3.x); a1 += bfhi(u3.x); a2 += bflo(u3.y); a3 += bfhi(u3.y);
        a4 += bflo(u3.z); a5 += bfhi(u3.z); a6 += bflo(u3.w); a7 += bfhi(u3.w);
    }
    for (; k < d; k += 4) {                   // predicated quad tail
        int kk = k + grp;
        int ia = (int)row[kk < d ? kk : (d - 1)];
        uint4 u = yq[ia * 16 + c];
        if (kk >= d) { u.x = 0u; u.y = 0u; u.z = 0u; u.w = 0u; }
        a0 += bflo(u.x); a1 += bfhi(u.x); a2 += bflo(u.y); a3 += bfhi(u.y);
        a4 += bflo(u.z); a5 += bfhi(u.z); a6 += bflo(u.w); a7 += bfhi(u.w);
    }
    // cross-group butterfly: lanes {c, c+16, c+32, c+48} hold disjoint rows
    a0 += __shfl_xor(a0, 16); a1 += __shfl_xor(a1, 16);
    a2 += __shfl_xor(a2, 16); a3 += __shfl_xor(a3, 16);
    a4 += __shfl_xor(a4, 16); a5 += __shfl_xor(a5, 16);
    a6 += __shfl_xor(a6, 16); a7 += __shfl_xor(a7, 16);
    a0 += __shfl_xor(a0, 32); a1 += __shfl_xor(a1, 32);
    a2 += __shfl_xor(a2, 32); a3 += __shfl_xor(a3, 32);
    a4 += __shfl_xor(a4, 32); a5 += __shfl_xor(a5, 32);
    a6 += __shfl_xor(a6, 32); a7 += __shfl_xor(a7, 32);
    if (grp == 0) {
        float inv = 1.0f / fmaxf((float)d_true, 1.0f);
        uint4 o;
        o.x = (unsigned)f2bf(a0 * inv) | ((unsigned)f2bf(a1 * inv) << 16);
        o.y = (unsigned)f2bf(a2 * inv) | ((unsigned)f2bf(a3 * inv) << 16);
        o.z = (unsigned)f2bf(a4 * inv) | ((unsigned)f2bf(a5 * inv) << 16);
        o.w = (unsigned)f2bf(a6 * inv) | ((unsigned)f2bf(a7 * inv) << 16);
        ((uint4*)agg)[wid * 16 + c] = o;
    }
}

// --- k3: MFMA GEMM  out = [agg | feat] @ [W_l ; W_r]^T + b  (fp32 out) -----
// (R2-verified form.) A-frag: lane holds A[m=lane&15][k=kt*32+(lane>>4)*8+j];
// kt<4 from agg, kt>=4 from feat_bf. C/D: col=lane&15, row=(lane>>4)*4+r
__global__ __launch_bounds__(256) void gemm_out_kernel(
        const bf16_t* __restrict__ agg,
        const bf16_t* __restrict__ feat_bf,
        const bf16_t* __restrict__ Bp,
        const float* __restrict__ bl,
        float* __restrict__ out) {
    int wid = blockIdx.x * 4 + (threadIdx.x >> 6);   // 16-row M-tile
    if (wid >= N_NODES / 16) return;
    int lane = threadIdx.x & 63;
    int m    = lane & 15;
    int quad = lane >> 4;
    int row0 = wid * 16;

    floatx4 acc[8];
    floatx4 zf = {0.f, 0.f, 0.f, 0.f};
#pragma unroll
    for (int nt = 0; nt < 8; ++nt) acc[nt] = zf;

    const short8* bp = (const short8*)Bp;
#pragma unroll
    for (int kt = 0; kt < 8; ++kt) {
        const bf16_t* abase = (kt < 4)
            ? (agg     + (size_t)(row0 + m) * HIDDEN + kt * 32 + quad * 8)
            : (feat_bf + (size_t)(row0 + m) * HIDDEN + (kt - 4) * 32 + quad * 8);
        short8 afrag = *(const short8*)abase;
#pragma unroll
        for (int nt = 0; nt < 8; ++nt) {
            short8 bfrag = bp[(kt * 8 + nt) * 64 + lane];
            acc[nt] = __builtin_amdgcn_mfma_f32_16x16x32_bf16(afrag, bfrag, acc[nt], 0, 0, 0);
        }
    }
    int col = lane & 15;
#pragma unroll
    for (int nt = 0; nt < 8; ++nt) {
        float b = bl[nt * 16 + col];
#pragma unroll
        for (int r = 0; r < 4; ++r) {
            int row = row0 + quad * 4 + r;
            out[(size_t)row * HIDDEN + nt * 16 + col] = acc[nt][r] + b;
        }
    }
}

extern "C" void kernel_launch(void* const* d_in, const int* in_sizes, int n_in,
                              void* d_out, int out_size, void* d_ws, size_t ws_size,
                              hipStream_t stream) {
    const float* feat = (const float*)d_in[0];
    const int*   eidx = (const int*)d_in[1];
    const float* Wl   = (const float*)d_in[2];
    const float* bl   = (const float*)d_in[3];
    const float* Wr   = (const float*)d_in[4];
    float* out = (float*)d_out;

    // workspace layout (~15 MB; ws is 256 MiB); all sections 16B-aligned
    int*            deg     = (int*)d_ws;                                   // 20000*16 int
    unsigned short* bucket  = (unsigned short*)(deg + N_NODES * DEG_PAD);   // 20000*96 u16
    bf16_t*         Bp      = (bf16_t*)(bucket + (size_t)N_NODES * CAP);    // 32768 bf16
    bf16_t*         feat_bf = Bp + 2 * HIDDEN * HIDDEN;                     // 20000*128 bf16
    bf16_t*         agg     = feat_bf + (size_t)N_NODES * HIDDEN;           // 20000*128 bf16

    hipMemsetAsync(deg, 0, (size_t)N_NODES * DEG_PAD * sizeof(int), stream);

    prep_fill_kernel<<<N_EDGES / 256, 256, 0, stream>>>(
        feat, Wl, Wr, eidx, feat_bf, Bp, deg, bucket);
    agg_kernel<<<(N_NODES * 64) / 256, 256, 0, stream>>>(
        feat_bf, deg, bucket, agg);
    gemm_out_kernel<<<(N_NODES / 16 + 3) / 4, 256, 0, stream>>>(
        agg, feat_bf, Bp, bl, out);
}